// Round 10
// baseline (443.242 us; speedup 1.0000x reference)
//
#include <hip/hip_runtime.h>
#include <math.h>

// Problem constants: B=2, T=2048, E=1024, H=16, D=64; M = B*T = 4096
#define MM   4096
#define TT   2048
#define HH   16

typedef __bf16 bf16x8 __attribute__((ext_vector_type(8)));
typedef float f32x4 __attribute__((ext_vector_type(4)));

// async global->LDS, 16B per lane; LDS dest = wave-uniform base + lane*16
__device__ __forceinline__ void g2l16(const void* g, void* l) {
    __builtin_amdgcn_global_load_lds(
        (__attribute__((address_space(1))) void*)g,
        (__attribute__((address_space(3))) void*)l, 16, 0, 0);
}

// ---- raw transcendentals (guarded; libm fallback). Without -ffast-math the
// libm versions lower to multi-instruction OCML guard sequences — 3-4x cost.
#if __has_builtin(__builtin_amdgcn_exp2f)
__device__ __forceinline__ float fexp2(float x) { return __builtin_amdgcn_exp2f(x); }
#else
__device__ __forceinline__ float fexp2(float x) { return exp2f(x); }
#endif
#if __has_builtin(__builtin_amdgcn_logf)
__device__ __forceinline__ float flog2(float x) { return __builtin_amdgcn_logf(x); }
#else
__device__ __forceinline__ float flog2(float x) { return log2f(x); }
#endif
#if __has_builtin(__builtin_amdgcn_sqrtf)
__device__ __forceinline__ float fsqrt_(float x) { return __builtin_amdgcn_sqrtf(x); }
#else
__device__ __forceinline__ float fsqrt_(float x) { return sqrtf(x); }
#endif
#if __has_builtin(__builtin_amdgcn_rcpf)
__device__ __forceinline__ float frcp_(float x) { return __builtin_amdgcn_rcpf(x); }
#else
__device__ __forceinline__ float frcp_(float x) { return 1.0f / x; }
#endif
#if __has_builtin(__builtin_amdgcn_rsqf)
__device__ __forceinline__ float frsq_(float x) { return __builtin_amdgcn_rsqf(x); }
#else
__device__ __forceinline__ float frsq_(float x) { return rsqrtf(x); }
#endif

// fast GELU (tanh form, abs err ~1e-3; ref tolerance 0.25 and downstream
// weights are 0.02-scale -> negligible). Replaces libm erff (~35 VALU ops).
__device__ __forceinline__ float gelu_f(float x) {
    float u = 0.7978845608028654f * fmaf(0.044715f * x, x * x, x);
    u = fminf(fmaxf(u, -15.f), 15.f);
    float t = fexp2(-2.885390081777927f * u);     // e^{-2u}
    return 0.5f * x * (1.f + (1.f - t) * frcp_(1.f + t));
}

// ---------------------------------------------------------------- reductions
__device__ __forceinline__ float blockSum256(float v, volatile float* sb) {
    int lane = threadIdx.x & 63, w = threadIdx.x >> 6;
#pragma unroll
    for (int o = 32; o; o >>= 1) v += __shfl_xor(v, o);
    if (lane == 0) sb[w] = v;
    __syncthreads();
    v = sb[0] + sb[1] + sb[2] + sb[3];
    __syncthreads();
    return v;
}

// ---------------------------------------------------------------- block_norm -> bf16 (ldo-wide, zero pad)
__global__ __launch_bounds__(256) void block_norm_bf_k(
    const float* __restrict__ in, int ld,
    __bf16* __restrict__ out, int ldo,
    const float* __restrict__ lw, const float* __restrict__ lb,
    const float* __restrict__ curv)
{
    int row = blockIdx.x;
    const float* x = in + (size_t)row * ld;
    __bf16* o = out + (size_t)row * ldo;
    __shared__ float sb[4];
    int tid = threadIdx.x;
    float v[4]; float s1 = 0.f, s2 = 0.f;
#pragma unroll
    for (int r = 0; r < 4; r++) {
        float t = x[tid + 256 * r];
        v[r] = t; s1 += t; s2 += t * t;
    }
    s1 = blockSum256(s1, sb);
    s2 = blockSum256(s2, sb);
    float mean = s1 * (1.f / 1024.f);
    float var  = s2 * (1.f / 1024.f) - mean * mean;
    float rs = rsqrtf(var + 1e-5f);
    float y[4]; float ssq = 0.f;
#pragma unroll
    for (int r = 0; r < 4; r++) {
        int i = tid + 256 * r;
        float t = (v[r] - mean) * rs * lw[i] + lb[i];
        y[r] = t; ssq += t * t;
    }
    ssq = blockSum256(ssq, sb);
#pragma unroll
    for (int r = 0; r < 4; r++) o[1 + tid + 256 * r] = (__bf16)y[r];
    if (tid == 0) o[0] = (__bf16)sqrtf(expf(*curv) + ssq);
    if (tid < ldo - 1025) o[1025 + tid] = (__bf16)0.f;   // zero pad cols 1025..ldo-1
}

// ---------------------------------------------------------------- final out: sum split-K halves -> out[...,1:], x0 col
__global__ __launch_bounds__(256) void out_final_k(
    float* __restrict__ out, const float* __restrict__ P, const float* __restrict__ P2,
    const float* __restrict__ curv)
{
    int row = blockIdx.x;
    const float* p  = P  + (size_t)row * 1024;
    const float* p2 = P2 + (size_t)row * 1024;
    float* o = out + (size_t)row * 1025;
    __shared__ float sb[4];
    int tid = threadIdx.x;
    float v[4]; float s = 0.f;
#pragma unroll
    for (int r = 0; r < 4; r++) {
        float t = p[tid + 256 * r] + p2[tid + 256 * r];
        v[r] = t; s += t * t;
    }
    s = blockSum256(s, sb);
#pragma unroll
    for (int r = 0; r < 4; r++) o[1 + tid + 256 * r] = v[r];
    if (tid == 0) o[0] = sqrtf(expf(*curv) + s);
}

// ---------------------------------------------------------------- h tail (3 ragged cols) + x0 + pad (stride 4224)
// h layout (permuted, aligned): cols 0..4095 = gelu(h_1..h_4096), cols
// 4096..4098 = gelu(h_4097..4099) [here], col 4099 = x0, 4100..4223 = 0.
__global__ __launch_bounds__(256) void row_x0_tail_k(
    __bf16* __restrict__ h,
    const __bf16* __restrict__ ln,      // ln2, stride 1088 (zero-padded past 1025)
    const __bf16* __restrict__ Bt,      // meT, stride 1088
    const float* __restrict__ bias,     // b_me (4099)
    const float* __restrict__ curv)
{
    int row = blockIdx.x;
    __bf16* base = h + (size_t)row * 4224;
    const __bf16* lnr = ln + (size_t)row * 1088;
    const __bf16* B0 = Bt + (size_t)4096 * 1088;
    const __bf16* B1 = Bt + (size_t)4097 * 1088;
    const __bf16* B2 = Bt + (size_t)4098 * 1088;
    __shared__ float sb[4];
    float d0 = 0.f, d1 = 0.f, d2 = 0.f;
    for (int i = threadIdx.x; i < 1088; i += 256) {
        float a = (float)lnr[i];
        d0 += a * (float)B0[i];
        d1 += a * (float)B1[i];
        d2 += a * (float)B2[i];
    }
    d0 = blockSum256(d0, sb);
    d1 = blockSum256(d1, sb);
    d2 = blockSum256(d2, sb);
    float t3[3] = {d0 + bias[4096], d1 + bias[4097], d2 + bias[4098]};
    float ssq_t = 0.f;
#pragma unroll
    for (int j = 0; j < 3; j++) {
        float v = gelu_f(t3[j]);
        t3[j] = v; ssq_t += v * v;
    }
    if (threadIdx.x == 0) {
        base[4096] = (__bf16)t3[0];
        base[4097] = (__bf16)t3[1];
        base[4098] = (__bf16)t3[2];
    }
    float s = 0.f;
    for (int i = threadIdx.x; i < 4096; i += 256) { float t = (float)base[i]; s += t * t; }
    s = blockSum256(s, sb) + ssq_t;
    if (threadIdx.x == 0) base[4099] = (__bf16)sqrtf(expf(*curv) + s);   // x0 col
    if (threadIdx.x < 124) base[4100 + threadIdx.x] = (__bf16)0.f;       // zero pad
}

// ---------------------------------------------------------------- weight convert + transpose
// ROT: destination k index rotated by -1 mod K (k=0 -> K-1).
template<bool ROT>
__global__ __launch_bounds__(256) void wt_k(
    const float* __restrict__ W, int K, int N,
    __bf16* __restrict__ Wt, int Kp)
{
    __shared__ float s[32][33];
    int tx = threadIdx.x & 31, ty = threadIdx.x >> 5;    // 32 x 8
    int k0 = blockIdx.x * 32, n0 = blockIdx.y * 32;
#pragma unroll
    for (int r = 0; r < 4; r++) {
        int k = k0 + ty + 8 * r, n = n0 + tx;
        s[ty + 8 * r][tx] = (k < K && n < N) ? W[(size_t)k * N + n] : 0.f;
    }
    __syncthreads();
#pragma unroll
    for (int r = 0; r < 4; r++) {
        int n = n0 + ty + 8 * r, k = k0 + tx;
        int kd = (ROT && k < K) ? ((k == 0) ? (K - 1) : (k - 1)) : k;
        if (n < N) Wt[(size_t)n * Kp + kd] = (__bf16)s[tx][ty + 8 * r];
    }
}

// ---------------------------------------------------------------- bf16 MFMA GEMM 256x256, BK=32, 4-deep RING
// (unchanged from R9 — see notes there)
template<bool BIAS, bool GELU, bool OUTBF>
__global__ __launch_bounds__(512, 2) void mgemm256r_k(
    const __bf16* __restrict__ A, int lda,
    const __bf16* __restrict__ Bt, int ldb,
    const float* __restrict__ bias,
    void* __restrict__ Cout, int ldc,
    int N, int Kp, int nT)
{
    __shared__ __bf16 sAB[65536];   // A: 4 x 8192 elems | B: +32768
    const int tid = threadIdx.x;
    const int w = tid >> 6, lane = tid & 63;
    const int wm = w >> 2, wn = w & 3;
    const int lr = lane & 15, lq = lane >> 4;

    const int bid = blockIdx.x;
    const int xcd = bid & 7, loc = bid >> 3;
    const int nH = nT >> 1;
    const int mH = (gridDim.x >> 3) / nH;
    const int mt = (xcd >> 1) * mH + loc / nH;
    const int nt = (xcd & 1) * nH + loc % nH;
    const int m0 = mt * 256, n0 = nt * 256;

    const int rr  = tid >> 2;                       // 0..127
    const int csw = ((tid & 3) ^ ((rr >> 1) & 3)) << 3;   // elems
    const __bf16* gA[2]; const __bf16* gB[2];
#pragma unroll
    for (int c = 0; c < 2; c++) {
        gA[c] = A + (size_t)(m0 + c * 128 + rr) * lda + csw;
        gB[c] = Bt + (size_t)(n0 + c * 128 + rr) * ldb + csw;
    }
    char* lbase = (char*)sAB;
    const int wdst = w * 1024;                      // bytes within (sub, c) slice

    const int arowb = wm * 128 + lr;
    const int brow  = wn * 64 + lr;
    const int aoff = ((lq ^ ((arowb >> 1) & 3)) << 3);
    const int boff = ((lq ^ ((brow  >> 1) & 3)) << 3);

    f32x4 zero = {0.f, 0.f, 0.f, 0.f};
    f32x4 acc[8][4];
#pragma unroll
    for (int i = 0; i < 8; i++)
#pragma unroll
        for (int j = 0; j < 4; j++) acc[i][j] = zero;

    const int NTt = Kp >> 5;

    auto stage = [&](int s) {
        const int sb = (s & 3) * 16384;             // bytes
        const int ko = s << 5;                      // elems
#pragma unroll
        for (int c = 0; c < 2; c++) {
            g2l16(gA[c] + ko, lbase + sb + c * 8192 + wdst);
            g2l16(gB[c] + ko, lbase + 65536 + sb + c * 8192 + wdst);
        }
    };

    stage(0); stage(1); stage(2);
    asm volatile("s_waitcnt vmcnt(8)" ::: "memory");
    __builtin_amdgcn_s_barrier();

    for (int t = 0; t < NTt; ++t) {
        if (t + 3 < NTt) stage(t + 3);
        const __bf16* pA = sAB + (t & 3) * 8192;
        const __bf16* pB = sAB + 32768 + (t & 3) * 8192;
        bf16x8 af[8], bf[4];
#pragma unroll
        for (int i = 0; i < 8; i++) af[i] = *(const bf16x8*)&pA[(arowb + i * 16) * 32 + aoff];
#pragma unroll
        for (int j = 0; j < 4; j++) bf[j] = *(const bf16x8*)&pB[(brow + j * 16) * 32 + boff];
        __builtin_amdgcn_s_setprio(1);
#pragma unroll
        for (int i = 0; i < 8; i++)
#pragma unroll
            for (int j = 0; j < 4; j++)
                acc[i][j] = __builtin_amdgcn_mfma_f32_16x16x32_bf16(af[i], bf[j], acc[i][j], 0, 0, 0);
        __builtin_amdgcn_s_setprio(0);
        if (t + 3 < NTt)      { asm volatile("s_waitcnt vmcnt(8)" ::: "memory"); }
        else if (t + 2 < NTt) { asm volatile("s_waitcnt vmcnt(4)" ::: "memory"); }
        else                  { asm volatile("s_waitcnt vmcnt(0) lgkmcnt(0)" ::: "memory"); }
        __builtin_amdgcn_s_barrier();
    }

#pragma unroll
    for (int j = 0; j < 4; j++) {
        const int n = n0 + wn * 64 + j * 16 + lr;
        if (n < N) {
            const float bv = BIAS ? bias[n] : 0.f;
#pragma unroll
            for (int i = 0; i < 8; i++) {
#pragma unroll
                for (int r = 0; r < 4; r++) {
                    const int m = m0 + wm * 128 + i * 16 + lq * 4 + r;
                    float v = acc[i][j][r] + bv;
                    if (GELU) v = gelu_f(v);
                    if (OUTBF) ((__bf16*)Cout)[(size_t)m * ldc + n] = (__bf16)v;
                    else       ((float*)Cout)[(size_t)m * ldc + n] = v;
                }
            }
        }
    }
}

// ---------------------------------------------------------------- bf16 MFMA GEMM 128x128, BK=32, TRIPLE-buffered
// counted-vmcnt + 2D XCD chunking. SPLITK: grid doubled; blocks >= G compute
// the second K-half (A/Bt advanced by Kp elems) into Cout2, no bias/skip.
template<bool BIAS, bool GELU, bool SKIP, bool OUTBF, bool SPLITK>
__global__ __launch_bounds__(256, 3) void mgemm128_k(
    const __bf16* __restrict__ A, int lda,
    const __bf16* __restrict__ Bt, int ldb,
    const float* __restrict__ bias,
    const float* __restrict__ skip, int ldskip,
    void* __restrict__ Cout, int ldc, void* __restrict__ Cout2,
    int N, int Kp, int nT)                             // Kp multiple of 32, NT>=3
{
    __shared__ __bf16 sAB[24576];   // A: 3 x 4096 elems | B: 12288 + 3 x 4096
    const int tid = threadIdx.x;
    const int w = tid >> 6, lane = tid & 63;
    const int wm = w >> 1, wn = w & 1;
    const int lr = lane & 15, lq = lane >> 4;

    int bid = blockIdx.x;
    int kh = 0;
    const int G = SPLITK ? (gridDim.x >> 1) : gridDim.x;
    if (SPLITK && bid >= G) { kh = 1; bid -= G; }
    if (SPLITK && kh) { A += Kp; Bt += Kp; }

    // 2D XCD chunking (bijective)
    const int xcd = bid & 7, loc = bid >> 3;
    const int nH = nT >> 1;
    const int mH = (G >> 3) / nH;
    const int mt = (xcd >> 1) * mH + loc / nH;
    const int nt = (xcd & 1) * nH + loc % nH;
    const int m0 = mt * 128, n0 = nt * 128;

    const int rr  = tid >> 2;                       // 0..63
    const int csw = ((tid & 3) ^ ((rr >> 1) & 3)) << 3;   // elems
    const __bf16* gA[2]; const __bf16* gB[2];
#pragma unroll
    for (int c = 0; c < 2; c++) {
        gA[c] = A + (size_t)(m0 + c * 64 + rr) * lda + csw;
        gB[c] = Bt + (size_t)(n0 + c * 64 + rr) * ldb + csw;
    }
    const int wst = w * 512;                        // wave slice within a load-chunk

    const int off = (lq ^ ((lr >> 1) & 3)) << 3;
    const int arow = wm * 64 + lr;
    const int brow = wn * 64 + lr;

    f32x4 zero = {0.f, 0.f, 0.f, 0.f};
    f32x4 acc[4][4];
#pragma unroll
    for (int i = 0; i < 4; i++)
#pragma unroll
        for (int j = 0; j < 4; j++) acc[i][j] = zero;

    const int NT = Kp >> 5;
#pragma unroll
    for (int c = 0; c < 2; c++) {
        g2l16(gA[c], sAB + c * 2048 + wst);
        g2l16(gB[c], sAB + 12288 + c * 2048 + wst);
    }
#pragma unroll
    for (int c = 0; c < 2; c++) {
        g2l16(gA[c] + 32, sAB + 4096 + c * 2048 + wst);
        g2l16(gB[c] + 32, sAB + 12288 + 4096 + c * 2048 + wst);
    }
    asm volatile("s_waitcnt vmcnt(4)" ::: "memory");   // stage0 landed
    __builtin_amdgcn_s_barrier();

    int cur = 0;
    for (int kt = 0; kt < NT; ++kt) {
        if (kt + 2 < NT) {
            const int sbuf = (cur == 0) ? 2 : (cur - 1);      // (cur+2)%3
            const int ko = (kt + 2) << 5;
#pragma unroll
            for (int c = 0; c < 2; c++) {
                g2l16(gA[c] + ko, sAB + sbuf * 4096 + c * 2048 + wst);
                g2l16(gB[c] + ko, sAB + 12288 + sbuf * 4096 + c * 2048 + wst);
            }
        }
        const __bf16* pA = sAB + cur * 4096;
        const __bf16* pB = sAB + 12288 + cur * 4096;
        bf16x8 af[4], bf[4];
#pragma unroll
        for (int i = 0; i < 4; i++) af[i] = *(const bf16x8*)&pA[(arow + i * 16) * 32 + off];
#pragma unroll
        for (int j = 0; j < 4; j++) bf[j] = *(const bf16x8*)&pB[(brow + j * 16) * 32 + off];
        __builtin_amdgcn_s_setprio(1);
#pragma unroll
        for (int i = 0; i < 4; i++)
#pragma unroll
            for (int j = 0; j < 4; j++)
                acc[i][j] = __builtin_amdgcn_mfma_f32_16x16x32_bf16(af[i], bf[j], acc[i][j], 0, 0, 0);
        __builtin_amdgcn_s_setprio(0);
        if (kt + 2 < NT) { asm volatile("s_waitcnt vmcnt(4)" ::: "memory"); }
        else             { asm volatile("s_waitcnt vmcnt(0) lgkmcnt(0)" ::: "memory"); }
        __builtin_amdgcn_s_barrier();
        cur = (cur == 2) ? 0 : (cur + 1);
    }

    // ---- epilogue (split-K half 1: no bias/skip, writes Cout2)
    void* Cdst = (SPLITK && kh) ? Cout2 : Cout;
#pragma unroll
    for (int j = 0; j < 4; j++) {
        const int n = n0 + wn * 64 + j * 16 + lr;
        if (n < N) {
            const float bv = (BIAS && !(SPLITK && kh)) ? bias[n] : 0.f;
#pragma unroll
            for (int i = 0; i < 4; i++) {
#pragma unroll
                for (int r = 0; r < 4; r++) {
                    const int m = m0 + wm * 64 + i * 16 + lq * 4 + r;
                    float v = acc[i][j][r] + bv;
                    if (GELU) v = gelu_f(v);
                    if (SKIP && !(SPLITK && kh)) v += skip[(size_t)m * ldskip + n];
                    if (OUTBF) ((__bf16*)Cdst)[(size_t)m * ldc + n] = (__bf16)v;
                    else       ((float*)Cdst)[(size_t)m * ldc + n] = v;
                }
            }
        }
    }
}

// ---------------------------------------------------------------- RoPE in-place(q) + Kb bf16 + q/k norms
__global__ __launch_bounds__(256) void rope_k(
    float* __restrict__ QKV, const float* __restrict__ curv,
    float* __restrict__ qt, float* __restrict__ kt,
    __bf16* __restrict__ Kb, __bf16* __restrict__ Obf)
{
    int row = blockIdx.x;              // b*T + t
    int b = row >> 11, t = row & (TT - 1);
    int wv = threadIdx.x >> 6, d = threadIdx.x & 63;
    int j = d & 31;
    float fr = (float)t * powf(10000.0f, -(float)(2 * j) / 64.0f);
    float cv = cosf(fr), sv = sinf(fr);
    float sgn = (d < 32) ? sv : -sv;
    for (int h = wv; h < HH; h += 4) {
        float Kh = expf(curv[h]);
        float* base = QKV + (size_t)row * 3072 + h * 64;
        float q = base[d], k = base[1024 + d];
        float qp = __shfl_xor(q, 32);
        float kp = __shfl_xor(k, 32);
        float qr = q * cv + qp * sgn;
        float kr = k * cv + kp * sgn;
        base[d] = qr;                         // q roped in place (fp32 for hi/lo split)
        size_t oidx = ((size_t)(b * HH + h) * TT + t);
        Kb[oidx * 64 + d] = (__bf16)kr;       // roped k, bf16 head-major
        float sq = qr * qr, sk = kr * kr;
#pragma unroll
        for (int o = 32; o; o >>= 1) {
            sq += __shfl_xor(sq, o);
            sk += __shfl_xor(sk, o);
        }
        if (d == 0) {
            qt[oidx] = sqrtf(Kh + sq);
            kt[oidx] = sqrtf(Kh + sk);
        }
    }
    if (threadIdx.x < 48) Obf[(size_t)row * 1088 + 1040 + threadIdx.x] = (__bf16)0.f;
}

// ---------------------------------------------------------------- V transpose -> Vtb bf16 [bh][d][t] + vt norms
__global__ __launch_bounds__(256) void vtrans_k(
    const float* __restrict__ QKV, const float* __restrict__ curv,
    __bf16* __restrict__ Vtb, float* __restrict__ vt)
{
    __shared__ float sT[64 * 65];
    int bh = blockIdx.y; int h = bh & (HH - 1); int b = bh >> 4;
    int t0 = blockIdx.x * 64;
    int tid = threadIdx.x, w = tid >> 6, lane = tid & 63;
    float Kh = expf(curv[h]);
    const float* vbase = QKV + (size_t)(b * TT + t0) * 3072 + 2048 + h * 64;
#pragma unroll 4
    for (int i = 0; i < 16; i++) {
        int tr = w * 16 + i;
        float v = vbase[(size_t)tr * 3072 + lane];
        sT[lane * 65 + tr] = v;
        float s = v * v;
#pragma unroll
        for (int o = 32; o; o >>= 1) s += __shfl_xor(s, o);
        if (lane == 0) vt[(size_t)bh * TT + t0 + tr] = sqrtf(Kh + s);
    }
    __syncthreads();
    int d = tid >> 2, seg = tid & 3;
    const float* r = &sT[d * 65 + seg * 16];
    bf16x8 o0, o1;
#pragma unroll
    for (int i = 0; i < 8; i++) { o0[i] = (__bf16)r[i]; o1[i] = (__bf16)r[8 + i]; }
    __bf16* dst = Vtb + ((size_t)bh * 64 + d) * TT + t0 + seg * 16;
    *(bf16x8*)dst = o0;
    *(bf16x8*)(dst + 8) = o1;
}

// ---------------------------------------------------------------- MFMA flash hyperbolic attention (v9)
// v7 + (a) q/qt pre-scaled by invKh (dot' = dot*invKh straight from MFMA —
// saves the ratio multiply), (b) causal mask computed ONLY on the diagonal
// tile (all j <= NJ-2 tiles are fully unmasked: max col 64*qti-1 < q0 <= row).
// Score chain: 10 -> 7 VALU ops on ~94% of tiles.
__global__ __launch_bounds__(256, 3) void flash_k(
    const float* __restrict__ QKV,
    const __bf16* __restrict__ Kb, const __bf16* __restrict__ Vtb,
    const float* __restrict__ qt, const float* __restrict__ kt,
    const float* __restrict__ vt,
    const float* __restrict__ curv,
    __bf16* __restrict__ O)
{
    __shared__ __bf16 sK[2][4096];   // [buf][dgrp4][s=64][8 d]
    __shared__ __bf16 sVt[2][4096];  // [buf][tgrp4][d=64][8 t]
    __shared__ __bf16 sP[4 * 16 * 72];
    __shared__ float skt[2][64], svt[2][64];

    int bh = blockIdx.x; int h = bh & (HH - 1); int b = bh >> 4;
    int qti = 31 - (int)blockIdx.y;        // heavy blocks dispatch first
    int q0 = qti << 6;
    int NJ = qti + 1;
    float Kh = expf(curv[h]);
    float sqKh = sqrtf(Kh), msqK = -sqKh, invKh = 1.0f / Kh;
    const float* tok = QKV + (size_t)b * TT * 3072 + h * 64;  // roped q fp32
    const char* KbB = (const char*)Kb + (size_t)bh * TT * 128;
    const char* VtB = (const char*)Vtb + (size_t)bh * 64 * (TT * 2);
    const float* qtp = qt + (size_t)bh * TT;
    const float* ktp = kt + (size_t)bh * TT;
    const float* vtp = vt + (size_t)bh * TT;

    int tid = threadIdx.x;
    int w = tid >> 6, lane = tid & 63;
    int m = lane & 15, quad = lane >> 4;
    int myBase = q0 + 16 * w;              // all 4 waves share the same j-range
    __bf16* sPw = &sP[w * 16 * 72];

    // Q fragments (hi + lo bf16) PRE-SCALED by invKh; A-layout: A[m][k]
    bf16x8 qhi[2], qlo[2];
    {
        const float* qrow = tok + (size_t)(myBase + m) * 3072;
#pragma unroll
        for (int ks = 0; ks < 2; ks++) {
            const float* s = qrow + quad * 8 + 32 * ks;
            float4 f0 = *(const float4*)s;
            float4 f1 = *(const float4*)(s + 4);
            float fa[8] = {f0.x, f0.y, f0.z, f0.w, f1.x, f1.y, f1.z, f1.w};
#pragma unroll
            for (int jj = 0; jj < 8; jj++) {
                float sv = fa[jj] * invKh;
                __bf16 hv = (__bf16)sv;
                qhi[ks][jj] = hv;
                qlo[ks][jj] = (__bf16)(sv - (float)hv);
            }
        }
    }
    float qtv[4]; int qg[4];
#pragma unroll
    for (int r = 0; r < 4; r++) { qg[r] = myBase + quad * 4 + r; qtv[r] = qtp[qg[r]] * invKh; }

    f32x4 zero = {0.f, 0.f, 0.f, 0.f};
    f32x4 accO[4];
#pragma unroll
    for (int nt = 0; nt < 4; nt++) accO[nt] = zero;
    float lsumr[4] = {}, o0r[4] = {};

    // ---- prologue: stage tile 0 -> buf 0
    {
        const char* kg = KbB + (size_t)lane * 128 + w * 16;
        char* sKb = (char*)&sK[0][0] + w * 1024;
        g2l16(kg,      sKb);
        g2l16(kg + 64, sKb + 4096);
        const char* vg = VtB + (size_t)lane * (TT * 2) + w * 16;
        char* sVb = (char*)&sVt[0][0] + w * 1024;
        g2l16(vg,      sVb);
        g2l16(vg + 64, sVb + 4096);
    }
    if (tid < 64) skt[0][tid] = ktp[tid];
    else if (tid < 128) svt[0][tid - 64] = vtp[tid - 64];
    __syncthreads();

    // ---- full (unmasked) tiles: j = 0 .. NJ-2
    for (int j = 0; j < NJ - 1; ++j) {
        int cur = j & 1;
        // issue next-tile stage EARLY (always exists: j+1 <= NJ-1)
        {
            int sb2 = (j + 1) << 6;
            const char* kg = KbB + (size_t)(sb2 + lane) * 128 + w * 16;
            char* sKb = (char*)&sK[cur ^ 1][0] + w * 1024;
            g2l16(kg,      sKb);
            g2l16(kg + 64, sKb + 4096);
            const char* vg = VtB + (size_t)lane * (TT * 2) + sb2 * 2 + w * 16;
            char* sVb = (char*)&sVt[cur ^ 1][0] + w * 1024;
            g2l16(vg,      sVb);
            g2l16(vg + 64, sVb + 4096);
            if (tid < 64) skt[cur ^ 1][tid] = ktp[sb2 + tid];
            else if (tid < 128) svt[cur ^ 1][tid - 64] = vtp[sb2 + tid - 64];
        }

        // QK^T
        f32x4 accS[4];
#pragma unroll
        for (int nt = 0; nt < 4; nt++) accS[nt] = zero;
#pragma unroll
        for (int nt = 0; nt < 4; nt++) {
#pragma unroll
            for (int ksp = 0; ksp < 2; ksp++) {
                bf16x8 bk = *(const bf16x8*)&sK[cur][((ksp * 4 + quad) * 64 + nt * 16 + m) * 8];
                accS[nt] = __builtin_amdgcn_mfma_f32_16x16x32_bf16(qhi[ksp], bk, accS[nt], 0, 0, 0);
                accS[nt] = __builtin_amdgcn_mfma_f32_16x16x32_bf16(qlo[ksp], bk, accS[nt], 0, 0, 0);
            }
        }
        // score epilogue — NO mask, NO ratio multiply (pre-scaled)
#pragma unroll
        for (int nt = 0; nt < 4; nt++) {
            int col = nt * 16 + m;
            float ktv = skt[cur][col], vtv = svt[cur][col];
#pragma unroll
            for (int r = 0; r < 4; r++) {
                float ratio = fmaxf(fmaf(qtv[r], ktv, -accS[nt][r]), 1.0f + 1e-7f);
                float y = ratio + fsqrt_(fmaf(ratio, ratio, -1.0f));
                float p = fexp2(msqK * flog2(y));              // exp(-sqrt(K)*acosh)
                lsumr[r] += p;
                o0r[r] = fmaf(p, vtv, o0r[r]);
                sPw[(quad * 4 + r) * 72 + col] = (__bf16)p;
            }
        }
        __asm__ volatile("s_waitcnt lgkmcnt(0)" ::: "memory");
        // PV
#pragma unroll
        for (int ksp = 0; ksp < 2; ksp++) {
            bf16x8 aP = *(const bf16x8*)&sPw[m * 72 + ksp * 32 + quad * 8];
#pragma unroll
            for (int nt = 0; nt < 4; nt++) {
                bf16x8 bV = *(const bf16x8*)&sVt[cur][((ksp * 4 + quad) * 64 + nt * 16 + m) * 8];
                accO[nt] = __builtin_amdgcn_mfma_f32_16x16x32_bf16(aP, bV, accO[nt], 0, 0, 0);
            }
        }
        __syncthreads();   // drains vmcnt+lgkm: next-tile staging complete, buf reuse safe
    }

    // ---- diagonal tile j = NJ-1 (masked)
    {
        int cur = (NJ - 1) & 1;
        int sb = (NJ - 1) << 6;
        f32x4 accS[4];
#pragma unroll
        for (int nt = 0; nt < 4; nt++) accS[nt] = zero;
#pragma unroll
        for (int nt = 0; nt < 4; nt++) {
#pragma unroll
            for (int ksp = 0; ksp < 2; ksp++) {
                bf16x8 bk = *(const bf16x8*)&sK[cur][((ksp * 4 + quad) * 64 + nt * 16 + m) * 8];
                accS[nt] = __builtin_amdgcn_mfma_f32_16x16x32_bf16(qhi[ksp], bk, accS[nt], 0, 0, 0);
                accS[nt] = __builtin_amdgcn_mfma_f32_16x16x32_bf16(qlo[ksp], bk, accS[nt], 0, 0, 0);
            }
        }
#pragma unroll
        for (int nt = 0; nt < 4; nt++) {
            int col = nt * 16 + m;
            int sglob = sb + col;
            float ktv = skt[cur][col], vtv = svt[cur][col];
#pragma unroll
            for (int r = 0; r < 4; r++) {
                float ratio = fmaxf(fmaf(qtv[r], ktv, -accS[nt][r]), 1.0f + 1e-7f);
                float y = ratio + fsqrt_(fmaf(ratio, ratio, -1.0f));
                float pv = fexp2(msqK * flog2(y));
                float p = (sglob <= qg[r]) ? pv : 0.0f;
                lsumr[r] += p;
                o0r[r] = fmaf(p, vtv, o0r[r]);
                sPw[(quad * 4 + r) * 72 + col] = (__bf16)p;
            }
        }
        __asm__ volatile("s_waitcnt lgkmcnt(0)" ::: "memory");
#pragma unroll
        for (int ksp = 0; ksp < 2; ksp++) {
            bf16x8 aP = *(const bf16x8*)&sPw[m * 72 + ksp * 32 + quad * 8];
#pragma unroll
            for (int nt = 0; nt < 4; nt++) {
                bf16x8 bV = *(const bf16x8*)&sVt[cur][((ksp * 4 + quad) * 64 + nt * 16 + m) * 8];
                accO[nt] = __builtin_amdgcn_mfma_f32_16x16x32_bf16(aP, bV, accO[nt], 0, 0, 0);
            }
        }
    }

    // ---- final: reduce lsum/o0 over the 16 col-lanes, normalize, write ----
#pragma unroll
    for (int r = 0; r < 4; r++) {
#pragma unroll
        for (int off = 1; off < 16; off <<= 1) {
            lsumr[r] += __shfl_xor(lsumr[r], off);
            o0r[r]   += __shfl_xor(o0r[r], off);
        }
    }
#pragma unroll
    for (int r = 0; r < 4; r++) {
        float inv = frcp_(lsumr[r]);
        float o0f = o0r[r] * inv;
        float ov[4]; float part = 0.f;
#pragma unroll
        for (int nt = 0; nt < 4; nt++) { float t = accO[nt][r] * inv; ov[nt] = t; part += t * t; }
        part += __shfl_xor(part, 1);
        part += __shfl_xor(part, 2);
        part += __shfl_xor(part, 4);
        part += __shfl_xor(part, 8);
        float scale = sqKh * frsq_(fmaxf(o0f * o0f - part, 1e-12f));
        size_t orow = (size_t)(b * TT + qg[r]) * 1088 + h * 65;
        if (m == 0) O[orow] = (__bf16)(o0f * scale);
#pragma unroll
        for (int nt = 0; nt < 4; nt++) O[orow + 1 + nt * 16 + m] = (__bf16)(ov[nt] * scale);
    }
}

// ---------------------------------------------------------------- launch
extern "C" void kernel_launch(void* const* d_in, const int* in_sizes, int n_in,
                              void* d_out, int out_size, void* d_ws, size_t ws_size,
                              hipStream_t stream) {
    const float* x    = (const float*)d_in[0];
    const float* bc   = (const float*)d_in[1];
    const float* mc   = (const float*)d_in[2];
    const float* ac   = (const float*)d_in[3];
    const float* w_qkv = (const float*)d_in[4];
    const float* w_ap  = (const float*)d_in[5];
    const float* b_ap  = (const float*)d_in[6];
    const float* w_me  = (const float*)d_in[7];
    const float* b_me  = (const float*)d_in[8];
    const float* w_ms  = (const float*)d_in[9];
    const float* b_ms  = (const float*)d_in[10];
    const float* lnw  = (const float*)d_in[11];
    const float* lnb  = (const float*)d_in[12];
    float* out = (float*)d_out;
    float* ws  = (float*)d_ws;

    // workspace (floats), total ~96.5 MB.
    float* R      = ws;
    float* qkvbuf = R;                             // M*3072 fp32 (dead after flash)
    float* X2     = R;                             // M*1024 fp32 (written step 5)
    __bf16* h_bf  = (__bf16*)(R + 4194304);        // M*4224 bf16 -> ends 12,845,056
    float* p      = R + 12845056;
    __bf16* ln_bf = (__bf16*)p;  p += 2228224;     // M*1088 bf16 (dead after step 8)
    __bf16* o_bf  = (__bf16*)p;  p += 2228224;     // M*1088 bf16 (dead after step 5)
    __bf16* qkvT  = (__bf16*)p;  p += 1671168;     // 3072*1088 bf16 (dead after step 2)
    __bf16* apT   = (__bf16*)p;  p += 557056;      // 1024*1088 bf16 (dead after step 5)
    float*  meT_f = p;           p += 2229856;     // 4099*1088 bf16 (dead after step 8)
    float*  msT_f = p;           p += 2162688;     // 1024*4224 bf16 (after flash)
    float* Qt = p;               p += 2 * HH * TT;
    float* Kt = p;               p += 2 * HH * TT;
    float* Vt = p;
    __bf16* meT = (__bf16*)meT_f;
    __bf16* msT = (__bf16*)msT_f;
    __bf16* Kb  = (__bf16*)meT_f;   // 32*2048*64 bf16 <= meT slot; dead before wt_k(meT)
    __bf16* Vtb = (__bf16*)msT_f;   // same size      <= msT slot; dead before wt_k(msT)
    float* Pbuf  = (float*)ln_bf;   // M*1024 fp32 (ln_bf+o_bf slots, written step 9)
    float* Pbuf2 = (float*)qkvT;    // M*1024 fp32 (qkvT+apT+meT slots = 4.46M floats, written step 9)

    // 0. weight transposes needed before flash (zero-filled past K)
    wt_k<false><<<dim3(34, 96),  256, 0, stream>>>(w_qkv, 1025, 3072, qkvT, 1088);
    wt_k<false><<<dim3(34, 32),  256, 0, stream>>>(w_ap,  1040, 1024, apT,  1088);

    // 1. ln1 = block_norm(project(x)) -> bf16 (stride 1088, zero pad)
    block_norm_bf_k<<<MM, 256, 0, stream>>>(x, 1024, ln_bf, 1088, lnw, lnb, bc);
    // 2. qkv = ln1 @ w_qkv -> fp32 (M,3072)   [256^2 4-deep RING, 192 blocks]
    mgemm256r_k<false, false, false><<<dim3(192), 512, 0, stream>>>(
        ln_bf, 1088, qkvT, 1088, nullptr, qkvbuf, 3072, 3072, 1088, 12);
    // 3a. RoPE (q in place fp32, Kb bf16) + q/k norms + o_bf pad (cols 1040..1087)
    rope_k<<<MM, 256, 0, stream>>>(qkvbuf, ac, Qt, Kt, Kb, o_bf);
    // 3b. V transpose -> Vtb bf16 + v norms
    vtrans_k<<<dim3(32, 32), 256, 0, stream>>>(qkvbuf, ac, Vtb, Vt);
    // 4. MFMA flash attention -> o_t bf16 (M,1088)
    flash_k<<<dim3(2 * HH, 32), 256, 0, stream>>>(qkvbuf, Kb, Vtb, Qt, Kt, Vt, ac, o_bf);
    // 0b. remaining weight transposes (into the slots Kb/Vtb just vacated)
    wt_k<false><<<dim3(34, 129), 256, 0, stream>>>(w_me,  1025, 4099, meT, 1088);
    wt_k<true ><<<dim3(132, 32), 256, 0, stream>>>(w_ms,  4100, 1024, msT, 4224);  // rotated rows
    // 5. lx2[...,1:] = x + o_t @ w_attn_proj + b -> X2 fp32
    mgemm128_k<true, false, true, false, false><<<dim3(256), 256, 0, stream>>>(
        o_bf, 1088, apT, 1088, b_ap, x, 1024, X2, 1024, nullptr, 1024, 1088, 8);
    // 6. ln2 = block_norm(lx2) -> bf16
    block_norm_bf_k<<<MM, 256, 0, stream>>>(X2, 1024, ln_bf, 1088, lnw, lnb, bc);
    // 7. h[0..4095] = gelu(ln2 @ w_mlp_expand + b) -> bf16, ALIGNED   [256^2 RING, 256 blocks]
    mgemm256r_k<true, true, true><<<dim3(256), 512, 0, stream>>>(
        ln_bf, 1088, meT, 1088, b_me, (void*)h_bf, 4224, 4096, 1088, 16);
    // 8. h cols 4096..4098 (ragged tail) + x0 col 4099 + pad
    row_x0_tail_k<<<MM, 256, 0, stream>>>(h_bf, ln_bf, meT, b_me, mc);
    // 9. split-K=2 shrink in ONE dispatch (512 blocks, 2/CU co-resident):
    //    half0 -> Pbuf (bias+skip), half1 -> Pbuf2 (plain)
    mgemm128_k<true, false, true, false, true><<<dim3(512), 256, 0, stream>>>(
        h_bf, 4224, msT, 4224, b_ms, X2, 1024, (void*)Pbuf, 1024, (void*)Pbuf2, 1024, 2112, 8);
    // 10. out[...,1:] = Pbuf + Pbuf2, out[...,0] = x0
    out_final_k<<<MM, 256, 0, stream>>>(out, Pbuf, Pbuf2, bc);
}

// Round 11
// 437.310 us; speedup vs baseline: 1.0136x; 1.0136x over previous
//
#include <hip/hip_runtime.h>
#include <math.h>

// Problem constants: B=2, T=2048, E=1024, H=16, D=64; M = B*T = 4096
#define MM   4096
#define TT   2048
#define HH   16

typedef __bf16 bf16x8 __attribute__((ext_vector_type(8)));
typedef float f32x4 __attribute__((ext_vector_type(4)));

// async global->LDS, 16B per lane; LDS dest = wave-uniform base + lane*16
__device__ __forceinline__ void g2l16(const void* g, void* l) {
    __builtin_amdgcn_global_load_lds(
        (__attribute__((address_space(1))) void*)g,
        (__attribute__((address_space(3))) void*)l, 16, 0, 0);
}

// ---- raw transcendentals (guarded; libm fallback). Without -ffast-math the
// libm versions lower to multi-instruction OCML guard sequences — 3-4x cost.
#if __has_builtin(__builtin_amdgcn_exp2f)
__device__ __forceinline__ float fexp2(float x) { return __builtin_amdgcn_exp2f(x); }
#else
__device__ __forceinline__ float fexp2(float x) { return exp2f(x); }
#endif
#if __has_builtin(__builtin_amdgcn_logf)
__device__ __forceinline__ float flog2(float x) { return __builtin_amdgcn_logf(x); }
#else
__device__ __forceinline__ float flog2(float x) { return log2f(x); }
#endif
#if __has_builtin(__builtin_amdgcn_sqrtf)
__device__ __forceinline__ float fsqrt_(float x) { return __builtin_amdgcn_sqrtf(x); }
#else
__device__ __forceinline__ float fsqrt_(float x) { return sqrtf(x); }
#endif
#if __has_builtin(__builtin_amdgcn_rcpf)
__device__ __forceinline__ float frcp_(float x) { return __builtin_amdgcn_rcpf(x); }
#else
__device__ __forceinline__ float frcp_(float x) { return 1.0f / x; }
#endif
#if __has_builtin(__builtin_amdgcn_rsqf)
__device__ __forceinline__ float frsq_(float x) { return __builtin_amdgcn_rsqf(x); }
#else
__device__ __forceinline__ float frsq_(float x) { return rsqrtf(x); }
#endif

// fast GELU (tanh form, abs err ~1e-3; ref tolerance 0.25 and downstream
// weights are 0.02-scale -> negligible). Replaces libm erff (~35 VALU ops).
__device__ __forceinline__ float gelu_f(float x) {
    float u = 0.7978845608028654f * fmaf(0.044715f * x, x * x, x);
    u = fminf(fmaxf(u, -15.f), 15.f);
    float t = fexp2(-2.885390081777927f * u);     // e^{-2u}
    return 0.5f * x * (1.f + (1.f - t) * frcp_(1.f + t));
}

// ---------------------------------------------------------------- reductions
__device__ __forceinline__ float blockSum256(float v, volatile float* sb) {
    int lane = threadIdx.x & 63, w = threadIdx.x >> 6;
#pragma unroll
    for (int o = 32; o; o >>= 1) v += __shfl_xor(v, o);
    if (lane == 0) sb[w] = v;
    __syncthreads();
    v = sb[0] + sb[1] + sb[2] + sb[3];
    __syncthreads();
    return v;
}

// ---------------------------------------------------------------- block_norm -> bf16 (ldo-wide, zero pad)
__global__ __launch_bounds__(256) void block_norm_bf_k(
    const float* __restrict__ in, int ld,
    __bf16* __restrict__ out, int ldo,
    const float* __restrict__ lw, const float* __restrict__ lb,
    const float* __restrict__ curv)
{
    int row = blockIdx.x;
    const float* x = in + (size_t)row * ld;
    __bf16* o = out + (size_t)row * ldo;
    __shared__ float sb[4];
    int tid = threadIdx.x;
    float v[4]; float s1 = 0.f, s2 = 0.f;
#pragma unroll
    for (int r = 0; r < 4; r++) {
        float t = x[tid + 256 * r];
        v[r] = t; s1 += t; s2 += t * t;
    }
    s1 = blockSum256(s1, sb);
    s2 = blockSum256(s2, sb);
    float mean = s1 * (1.f / 1024.f);
    float var  = s2 * (1.f / 1024.f) - mean * mean;
    float rs = rsqrtf(var + 1e-5f);
    float y[4]; float ssq = 0.f;
#pragma unroll
    for (int r = 0; r < 4; r++) {
        int i = tid + 256 * r;
        float t = (v[r] - mean) * rs * lw[i] + lb[i];
        y[r] = t; ssq += t * t;
    }
    ssq = blockSum256(ssq, sb);
#pragma unroll
    for (int r = 0; r < 4; r++) o[1 + tid + 256 * r] = (__bf16)y[r];
    if (tid == 0) o[0] = (__bf16)sqrtf(expf(*curv) + ssq);
    if (tid < ldo - 1025) o[1025 + tid] = (__bf16)0.f;   // zero pad cols 1025..ldo-1
}

// ---------------------------------------------------------------- final out: copy aligned P -> out[...,1:], x0 col
__global__ __launch_bounds__(256) void out_final_k(
    float* __restrict__ out, const float* __restrict__ P,
    const float* __restrict__ curv)
{
    int row = blockIdx.x;
    const float* p = P + (size_t)row * 1024;
    float* o = out + (size_t)row * 1025;
    __shared__ float sb[4];
    int tid = threadIdx.x;
    float v[4]; float s = 0.f;
#pragma unroll
    for (int r = 0; r < 4; r++) { float t = p[tid + 256 * r]; v[r] = t; s += t * t; }
    s = blockSum256(s, sb);
#pragma unroll
    for (int r = 0; r < 4; r++) o[1 + tid + 256 * r] = v[r];
    if (tid == 0) o[0] = sqrtf(expf(*curv) + s);
}

// ---------------------------------------------------------------- h tail (3 ragged cols) + x0 + pad (stride 4224)
// h layout (permuted, aligned): cols 0..4095 = gelu(h_1..h_4096), cols
// 4096..4098 = gelu(h_4097..4099) [here], col 4099 = x0, 4100..4223 = 0.
__global__ __launch_bounds__(256) void row_x0_tail_k(
    __bf16* __restrict__ h,
    const __bf16* __restrict__ ln,      // ln2, stride 1088 (zero-padded past 1025)
    const __bf16* __restrict__ Bt,      // meT, stride 1088
    const float* __restrict__ bias,     // b_me (4099)
    const float* __restrict__ curv)
{
    int row = blockIdx.x;
    __bf16* base = h + (size_t)row * 4224;
    const __bf16* lnr = ln + (size_t)row * 1088;
    const __bf16* B0 = Bt + (size_t)4096 * 1088;
    const __bf16* B1 = Bt + (size_t)4097 * 1088;
    const __bf16* B2 = Bt + (size_t)4098 * 1088;
    __shared__ float sb[4];
    float d0 = 0.f, d1 = 0.f, d2 = 0.f;
    for (int i = threadIdx.x; i < 1088; i += 256) {
        float a = (float)lnr[i];
        d0 += a * (float)B0[i];
        d1 += a * (float)B1[i];
        d2 += a * (float)B2[i];
    }
    d0 = blockSum256(d0, sb);
    d1 = blockSum256(d1, sb);
    d2 = blockSum256(d2, sb);
    float t3[3] = {d0 + bias[4096], d1 + bias[4097], d2 + bias[4098]};
    float ssq_t = 0.f;
#pragma unroll
    for (int j = 0; j < 3; j++) {
        float v = gelu_f(t3[j]);
        t3[j] = v; ssq_t += v * v;
    }
    if (threadIdx.x == 0) {
        base[4096] = (__bf16)t3[0];
        base[4097] = (__bf16)t3[1];
        base[4098] = (__bf16)t3[2];
    }
    float s = 0.f;
    for (int i = threadIdx.x; i < 4096; i += 256) { float t = (float)base[i]; s += t * t; }
    s = blockSum256(s, sb) + ssq_t;
    if (threadIdx.x == 0) base[4099] = (__bf16)sqrtf(expf(*curv) + s);   // x0 col
    if (threadIdx.x < 124) base[4100 + threadIdx.x] = (__bf16)0.f;       // zero pad
}

// ---------------------------------------------------------------- weight convert + transpose
// ROT: destination k index rotated by -1 mod K (k=0 -> K-1).
template<bool ROT>
__global__ __launch_bounds__(256) void wt_k(
    const float* __restrict__ W, int K, int N,
    __bf16* __restrict__ Wt, int Kp)
{
    __shared__ float s[32][33];
    int tx = threadIdx.x & 31, ty = threadIdx.x >> 5;    // 32 x 8
    int k0 = blockIdx.x * 32, n0 = blockIdx.y * 32;
#pragma unroll
    for (int r = 0; r < 4; r++) {
        int k = k0 + ty + 8 * r, n = n0 + tx;
        s[ty + 8 * r][tx] = (k < K && n < N) ? W[(size_t)k * N + n] : 0.f;
    }
    __syncthreads();
#pragma unroll
    for (int r = 0; r < 4; r++) {
        int n = n0 + ty + 8 * r, k = k0 + tx;
        int kd = (ROT && k < K) ? ((k == 0) ? (K - 1) : (k - 1)) : k;
        if (n < N) Wt[(size_t)n * Kp + kd] = (__bf16)s[tx][ty + 8 * r];
    }
}

// ---------------------------------------------------------------- bf16 MFMA GEMM 256x256, BK=32, 4-deep RING
template<bool BIAS, bool GELU, bool OUTBF>
__global__ __launch_bounds__(512, 2) void mgemm256r_k(
    const __bf16* __restrict__ A, int lda,
    const __bf16* __restrict__ Bt, int ldb,
    const float* __restrict__ bias,
    void* __restrict__ Cout, int ldc,
    int N, int Kp, int nT)
{
    __shared__ __bf16 sAB[65536];   // A: 4 x 8192 elems | B: +32768
    const int tid = threadIdx.x;
    const int w = tid >> 6, lane = tid & 63;
    const int wm = w >> 2, wn = w & 3;
    const int lr = lane & 15, lq = lane >> 4;

    const int bid = blockIdx.x;
    const int xcd = bid & 7, loc = bid >> 3;
    const int nH = nT >> 1;
    const int mH = (gridDim.x >> 3) / nH;
    const int mt = (xcd >> 1) * mH + loc / nH;
    const int nt = (xcd & 1) * nH + loc % nH;
    const int m0 = mt * 256, n0 = nt * 256;

    const int rr  = tid >> 2;                       // 0..127
    const int csw = ((tid & 3) ^ ((rr >> 1) & 3)) << 3;   // elems
    const __bf16* gA[2]; const __bf16* gB[2];
#pragma unroll
    for (int c = 0; c < 2; c++) {
        gA[c] = A + (size_t)(m0 + c * 128 + rr) * lda + csw;
        gB[c] = Bt + (size_t)(n0 + c * 128 + rr) * ldb + csw;
    }
    char* lbase = (char*)sAB;
    const int wdst = w * 1024;                      // bytes within (sub, c) slice

    const int arowb = wm * 128 + lr;
    const int brow  = wn * 64 + lr;
    const int aoff = ((lq ^ ((arowb >> 1) & 3)) << 3);
    const int boff = ((lq ^ ((brow  >> 1) & 3)) << 3);

    f32x4 zero = {0.f, 0.f, 0.f, 0.f};
    f32x4 acc[8][4];
#pragma unroll
    for (int i = 0; i < 8; i++)
#pragma unroll
        for (int j = 0; j < 4; j++) acc[i][j] = zero;

    const int NTt = Kp >> 5;

    auto stage = [&](int s) {
        const int sb = (s & 3) * 16384;             // bytes
        const int ko = s << 5;                      // elems
#pragma unroll
        for (int c = 0; c < 2; c++) {
            g2l16(gA[c] + ko, lbase + sb + c * 8192 + wdst);
            g2l16(gB[c] + ko, lbase + 65536 + sb + c * 8192 + wdst);
        }
    };

    stage(0); stage(1); stage(2);
    asm volatile("s_waitcnt vmcnt(8)" ::: "memory");
    __builtin_amdgcn_s_barrier();

    for (int t = 0; t < NTt; ++t) {
        if (t + 3 < NTt) stage(t + 3);
        const __bf16* pA = sAB + (t & 3) * 8192;
        const __bf16* pB = sAB + 32768 + (t & 3) * 8192;
        bf16x8 af[8], bf[4];
#pragma unroll
        for (int i = 0; i < 8; i++) af[i] = *(const bf16x8*)&pA[(arowb + i * 16) * 32 + aoff];
#pragma unroll
        for (int j = 0; j < 4; j++) bf[j] = *(const bf16x8*)&pB[(brow + j * 16) * 32 + boff];
        __builtin_amdgcn_s_setprio(1);
#pragma unroll
        for (int i = 0; i < 8; i++)
#pragma unroll
            for (int j = 0; j < 4; j++)
                acc[i][j] = __builtin_amdgcn_mfma_f32_16x16x32_bf16(af[i], bf[j], acc[i][j], 0, 0, 0);
        __builtin_amdgcn_s_setprio(0);
        if (t + 3 < NTt)      { asm volatile("s_waitcnt vmcnt(8)" ::: "memory"); }
        else if (t + 2 < NTt) { asm volatile("s_waitcnt vmcnt(4)" ::: "memory"); }
        else                  { asm volatile("s_waitcnt vmcnt(0) lgkmcnt(0)" ::: "memory"); }
        __builtin_amdgcn_s_barrier();
    }

#pragma unroll
    for (int j = 0; j < 4; j++) {
        const int n = n0 + wn * 64 + j * 16 + lr;
        if (n < N) {
            const float bv = BIAS ? bias[n] : 0.f;
#pragma unroll
            for (int i = 0; i < 8; i++) {
#pragma unroll
                for (int r = 0; r < 4; r++) {
                    const int m = m0 + wm * 128 + i * 16 + lq * 4 + r;
                    float v = acc[i][j][r] + bv;
                    if (GELU) v = gelu_f(v);
                    if (OUTBF) ((__bf16*)Cout)[(size_t)m * ldc + n] = (__bf16)v;
                    else       ((float*)Cout)[(size_t)m * ldc + n] = v;
                }
            }
        }
    }
}

// ---------------------------------------------------------------- bf16 MFMA GEMM 128x128, BK=32, TRIPLE-buffered
// counted-vmcnt + 2D XCD chunking (see R7/R8 notes).
template<bool BIAS, bool GELU, bool SKIP, bool OUTBF>
__global__ __launch_bounds__(256, 3) void mgemm128_k(
    const __bf16* __restrict__ A, int lda,
    const __bf16* __restrict__ Bt, int ldb,
    const float* __restrict__ bias,
    const float* __restrict__ skip, int ldskip,
    void* __restrict__ Cout, int ldc,
    int N, int Kp, int nT)                             // Kp multiple of 32, NT>=3
{
    __shared__ __bf16 sAB[24576];   // A: 3 x 4096 elems | B: 12288 + 3 x 4096
    const int tid = threadIdx.x;
    const int w = tid >> 6, lane = tid & 63;
    const int wm = w >> 1, wn = w & 1;
    const int lr = lane & 15, lq = lane >> 4;

    const int bid = blockIdx.x;
    const int xcd = bid & 7, loc = bid >> 3;
    const int nH = nT >> 1;
    const int mH = (gridDim.x >> 3) / nH;
    const int mt = (xcd >> 1) * mH + loc / nH;
    const int nt = (xcd & 1) * nH + loc % nH;
    const int m0 = mt * 128, n0 = nt * 128;

    const int rr  = tid >> 2;                       // 0..63
    const int csw = ((tid & 3) ^ ((rr >> 1) & 3)) << 3;   // elems
    const __bf16* gA[2]; const __bf16* gB[2];
#pragma unroll
    for (int c = 0; c < 2; c++) {
        gA[c] = A + (size_t)(m0 + c * 64 + rr) * lda + csw;
        gB[c] = Bt + (size_t)(n0 + c * 64 + rr) * ldb + csw;
    }
    const int wst = w * 512;                        // wave slice within a load-chunk

    const int off = (lq ^ ((lr >> 1) & 3)) << 3;
    const int arow = wm * 64 + lr;
    const int brow = wn * 64 + lr;

    f32x4 zero = {0.f, 0.f, 0.f, 0.f};
    f32x4 acc[4][4];
#pragma unroll
    for (int i = 0; i < 4; i++)
#pragma unroll
        for (int j = 0; j < 4; j++) acc[i][j] = zero;

    const int NT = Kp >> 5;
#pragma unroll
    for (int c = 0; c < 2; c++) {
        g2l16(gA[c], sAB + c * 2048 + wst);
        g2l16(gB[c], sAB + 12288 + c * 2048 + wst);
    }
#pragma unroll
    for (int c = 0; c < 2; c++) {
        g2l16(gA[c] + 32, sAB + 4096 + c * 2048 + wst);
        g2l16(gB[c] + 32, sAB + 12288 + 4096 + c * 2048 + wst);
    }
    asm volatile("s_waitcnt vmcnt(4)" ::: "memory");   // stage0 landed
    __builtin_amdgcn_s_barrier();

    int cur = 0;
    for (int kt = 0; kt < NT; ++kt) {
        if (kt + 2 < NT) {
            const int sbuf = (cur == 0) ? 2 : (cur - 1);      // (cur+2)%3
            const int ko = (kt + 2) << 5;
#pragma unroll
            for (int c = 0; c < 2; c++) {
                g2l16(gA[c] + ko, sAB + sbuf * 4096 + c * 2048 + wst);
                g2l16(gB[c] + ko, sAB + 12288 + sbuf * 4096 + c * 2048 + wst);
            }
        }
        const __bf16* pA = sAB + cur * 4096;
        const __bf16* pB = sAB + 12288 + cur * 4096;
        bf16x8 af[4], bf[4];
#pragma unroll
        for (int i = 0; i < 4; i++) af[i] = *(const bf16x8*)&pA[(arow + i * 16) * 32 + off];
#pragma unroll
        for (int j = 0; j < 4; j++) bf[j] = *(const bf16x8*)&pB[(brow + j * 16) * 32 + off];
        __builtin_amdgcn_s_setprio(1);
#pragma unroll
        for (int i = 0; i < 4; i++)
#pragma unroll
            for (int j = 0; j < 4; j++)
                acc[i][j] = __builtin_amdgcn_mfma_f32_16x16x32_bf16(af[i], bf[j], acc[i][j], 0, 0, 0);
        __builtin_amdgcn_s_setprio(0);
        if (kt + 2 < NT) { asm volatile("s_waitcnt vmcnt(4)" ::: "memory"); }
        else             { asm volatile("s_waitcnt vmcnt(0) lgkmcnt(0)" ::: "memory"); }
        __builtin_amdgcn_s_barrier();
        cur = (cur == 2) ? 0 : (cur + 1);
    }

#pragma unroll
    for (int j = 0; j < 4; j++) {
        const int n = n0 + wn * 64 + j * 16 + lr;
        if (n < N) {
            const float bv = BIAS ? bias[n] : 0.f;
#pragma unroll
            for (int i = 0; i < 4; i++) {
#pragma unroll
                for (int r = 0; r < 4; r++) {
                    const int m = m0 + wm * 64 + i * 16 + lq * 4 + r;
                    float v = acc[i][j][r] + bv;
                    if (GELU) v = gelu_f(v);
                    if (SKIP) v += skip[(size_t)m * ldskip + n];
                    if (OUTBF) ((__bf16*)Cout)[(size_t)m * ldc + n] = (__bf16)v;
                    else       ((float*)Cout)[(size_t)m * ldc + n] = v;
                }
            }
        }
    }
}

// ---------------------------------------------------------------- RoPE in-place(q) + Kb bf16 + q/k norms
__global__ __launch_bounds__(256) void rope_k(
    float* __restrict__ QKV, const float* __restrict__ curv,
    float* __restrict__ qt, float* __restrict__ kt,
    __bf16* __restrict__ Kb, __bf16* __restrict__ Obf)
{
    int row = blockIdx.x;              // b*T + t
    int b = row >> 11, t = row & (TT - 1);
    int wv = threadIdx.x >> 6, d = threadIdx.x & 63;
    int j = d & 31;
    float fr = (float)t * powf(10000.0f, -(float)(2 * j) / 64.0f);
    float cv = cosf(fr), sv = sinf(fr);
    float sgn = (d < 32) ? sv : -sv;
    for (int h = wv; h < HH; h += 4) {
        float Kh = expf(curv[h]);
        float* base = QKV + (size_t)row * 3072 + h * 64;
        float q = base[d], k = base[1024 + d];
        float qp = __shfl_xor(q, 32);
        float kp = __shfl_xor(k, 32);
        float qr = q * cv + qp * sgn;
        float kr = k * cv + kp * sgn;
        base[d] = qr;                         // q roped in place (fp32 for hi/lo split)
        size_t oidx = ((size_t)(b * HH + h) * TT + t);
        Kb[oidx * 64 + d] = (__bf16)kr;       // roped k, bf16 head-major
        float sq = qr * qr, sk = kr * kr;
#pragma unroll
        for (int o = 32; o; o >>= 1) {
            sq += __shfl_xor(sq, o);
            sk += __shfl_xor(sk, o);
        }
        if (d == 0) {
            qt[oidx] = sqrtf(Kh + sq);
            kt[oidx] = sqrtf(Kh + sk);
        }
    }
    if (threadIdx.x < 48) Obf[(size_t)row * 1088 + 1040 + threadIdx.x] = (__bf16)0.f;
}

// ---------------------------------------------------------------- V transpose -> Vtb bf16 [bh][d][t] + vt norms
__global__ __launch_bounds__(256) void vtrans_k(
    const float* __restrict__ QKV, const float* __restrict__ curv,
    __bf16* __restrict__ Vtb, float* __restrict__ vt)
{
    __shared__ float sT[64 * 65];
    int bh = blockIdx.y; int h = bh & (HH - 1); int b = bh >> 4;
    int t0 = blockIdx.x * 64;
    int tid = threadIdx.x, w = tid >> 6, lane = tid & 63;
    float Kh = expf(curv[h]);
    const float* vbase = QKV + (size_t)(b * TT + t0) * 3072 + 2048 + h * 64;
#pragma unroll 4
    for (int i = 0; i < 16; i++) {
        int tr = w * 16 + i;
        float v = vbase[(size_t)tr * 3072 + lane];
        sT[lane * 65 + tr] = v;
        float s = v * v;
#pragma unroll
        for (int o = 32; o; o >>= 1) s += __shfl_xor(s, o);
        if (lane == 0) vt[(size_t)bh * TT + t0 + tr] = sqrtf(Kh + s);
    }
    __syncthreads();
    int d = tid >> 2, seg = tid & 3;
    const float* r = &sT[d * 65 + seg * 16];
    bf16x8 o0, o1;
#pragma unroll
    for (int i = 0; i < 8; i++) { o0[i] = (__bf16)r[i]; o1[i] = (__bf16)r[8 + i]; }
    __bf16* dst = Vtb + ((size_t)bh * 64 + d) * TT + t0 + seg * 16;
    *(bf16x8*)dst = o0;
    *(bf16x8*)(dst + 8) = o1;
}

// ---------------------------------------------------------------- MFMA flash hyperbolic attention (v10)
// v9 + split score->PV fence: scores for cols 0..31 -> lgkmcnt -> PV ksp=0
// overlaps (MFMA pipe) with scores for cols 32..63 -> lgkmcnt -> PV ksp=1.
// The single lgkmcnt(0) previously serialized ALL 16 P-stores before ANY PV.
__global__ __launch_bounds__(256, 3) void flash_k(
    const float* __restrict__ QKV,
    const __bf16* __restrict__ Kb, const __bf16* __restrict__ Vtb,
    const float* __restrict__ qt, const float* __restrict__ kt,
    const float* __restrict__ vt,
    const float* __restrict__ curv,
    __bf16* __restrict__ O)
{
    __shared__ __bf16 sK[2][4096];   // [buf][dgrp4][s=64][8 d]
    __shared__ __bf16 sVt[2][4096];  // [buf][tgrp4][d=64][8 t]
    __shared__ __bf16 sP[4 * 16 * 72];
    __shared__ float skt[2][64], svt[2][64];

    int bh = blockIdx.x; int h = bh & (HH - 1); int b = bh >> 4;
    int qti = 31 - (int)blockIdx.y;        // heavy blocks dispatch first
    int q0 = qti << 6;
    int NJ = qti + 1;
    float Kh = expf(curv[h]);
    float sqKh = sqrtf(Kh), msqK = -sqKh, invKh = 1.0f / Kh;
    const float* tok = QKV + (size_t)b * TT * 3072 + h * 64;  // roped q fp32
    const char* KbB = (const char*)Kb + (size_t)bh * TT * 128;
    const char* VtB = (const char*)Vtb + (size_t)bh * 64 * (TT * 2);
    const float* qtp = qt + (size_t)bh * TT;
    const float* ktp = kt + (size_t)bh * TT;
    const float* vtp = vt + (size_t)bh * TT;

    int tid = threadIdx.x;
    int w = tid >> 6, lane = tid & 63;
    int m = lane & 15, quad = lane >> 4;
    int myBase = q0 + 16 * w;              // all 4 waves share the same j-range
    __bf16* sPw = &sP[w * 16 * 72];

    // Q fragments (hi + lo bf16) PRE-SCALED by invKh; A-layout: A[m][k]
    bf16x8 qhi[2], qlo[2];
    {
        const float* qrow = tok + (size_t)(myBase + m) * 3072;
#pragma unroll
        for (int ks = 0; ks < 2; ks++) {
            const float* s = qrow + quad * 8 + 32 * ks;
            float4 f0 = *(const float4*)s;
            float4 f1 = *(const float4*)(s + 4);
            float fa[8] = {f0.x, f0.y, f0.z, f0.w, f1.x, f1.y, f1.z, f1.w};
#pragma unroll
            for (int jj = 0; jj < 8; jj++) {
                float sv = fa[jj] * invKh;
                __bf16 hv = (__bf16)sv;
                qhi[ks][jj] = hv;
                qlo[ks][jj] = (__bf16)(sv - (float)hv);
            }
        }
    }
    float qtv[4]; int qg[4];
#pragma unroll
    for (int r = 0; r < 4; r++) { qg[r] = myBase + quad * 4 + r; qtv[r] = qtp[qg[r]] * invKh; }

    f32x4 zero = {0.f, 0.f, 0.f, 0.f};
    f32x4 accO[4];
#pragma unroll
    for (int nt = 0; nt < 4; nt++) accO[nt] = zero;
    float lsumr[4] = {}, o0r[4] = {};

    // ---- prologue: stage tile 0 -> buf 0
    {
        const char* kg = KbB + (size_t)lane * 128 + w * 16;
        char* sKb = (char*)&sK[0][0] + w * 1024;
        g2l16(kg,      sKb);
        g2l16(kg + 64, sKb + 4096);
        const char* vg = VtB + (size_t)lane * (TT * 2) + w * 16;
        char* sVb = (char*)&sVt[0][0] + w * 1024;
        g2l16(vg,      sVb);
        g2l16(vg + 64, sVb + 4096);
    }
    if (tid < 64) skt[0][tid] = ktp[tid];
    else if (tid < 128) svt[0][tid - 64] = vtp[tid - 64];
    __syncthreads();

    // ---- full (unmasked) tiles: j = 0 .. NJ-2
    for (int j = 0; j < NJ - 1; ++j) {
        int cur = j & 1;
        // issue next-tile stage EARLY (always exists: j+1 <= NJ-1)
        {
            int sb2 = (j + 1) << 6;
            const char* kg = KbB + (size_t)(sb2 + lane) * 128 + w * 16;
            char* sKb = (char*)&sK[cur ^ 1][0] + w * 1024;
            g2l16(kg,      sKb);
            g2l16(kg + 64, sKb + 4096);
            const char* vg = VtB + (size_t)lane * (TT * 2) + sb2 * 2 + w * 16;
            char* sVb = (char*)&sVt[cur ^ 1][0] + w * 1024;
            g2l16(vg,      sVb);
            g2l16(vg + 64, sVb + 4096);
            if (tid < 64) skt[cur ^ 1][tid] = ktp[sb2 + tid];
            else if (tid < 128) svt[cur ^ 1][tid - 64] = vtp[sb2 + tid - 64];
        }

        // QK^T (all 16 MFMA)
        f32x4 accS[4];
#pragma unroll
        for (int nt = 0; nt < 4; nt++) accS[nt] = zero;
#pragma unroll
        for (int nt = 0; nt < 4; nt++) {
#pragma unroll
            for (int ksp = 0; ksp < 2; ksp++) {
                bf16x8 bk = *(const bf16x8*)&sK[cur][((ksp * 4 + quad) * 64 + nt * 16 + m) * 8];
                accS[nt] = __builtin_amdgcn_mfma_f32_16x16x32_bf16(qhi[ksp], bk, accS[nt], 0, 0, 0);
                accS[nt] = __builtin_amdgcn_mfma_f32_16x16x32_bf16(qlo[ksp], bk, accS[nt], 0, 0, 0);
            }
        }
        // score half 0 (cols 0..31 = nt 0,1) -> PV ksp=0; half 1 -> PV ksp=1
#pragma unroll
        for (int half = 0; half < 2; half++) {
#pragma unroll
            for (int nt = 2 * half; nt < 2 * half + 2; nt++) {
                int col = nt * 16 + m;
                float ktv = skt[cur][col], vtv = svt[cur][col];
#pragma unroll
                for (int r = 0; r < 4; r++) {
                    float ratio = fmaxf(fmaf(qtv[r], ktv, -accS[nt][r]), 1.0f + 1e-7f);
                    float y = ratio + fsqrt_(fmaf(ratio, ratio, -1.0f));
                    float p = fexp2(msqK * flog2(y));          // exp(-sqrt(K)*acosh)
                    lsumr[r] += p;
                    o0r[r] = fmaf(p, vtv, o0r[r]);
                    sPw[(quad * 4 + r) * 72 + col] = (__bf16)p;
                }
            }
            __asm__ volatile("s_waitcnt lgkmcnt(0)" ::: "memory");
            {
                bf16x8 aP = *(const bf16x8*)&sPw[m * 72 + half * 32 + quad * 8];
#pragma unroll
                for (int nt = 0; nt < 4; nt++) {
                    bf16x8 bV = *(const bf16x8*)&sVt[cur][((half * 4 + quad) * 64 + nt * 16 + m) * 8];
                    accO[nt] = __builtin_amdgcn_mfma_f32_16x16x32_bf16(aP, bV, accO[nt], 0, 0, 0);
                }
            }
        }
        __syncthreads();   // drains vmcnt+lgkm: next-tile staging complete, buf reuse safe
    }

    // ---- diagonal tile j = NJ-1 (masked)
    {
        int cur = (NJ - 1) & 1;
        int sb = (NJ - 1) << 6;
        f32x4 accS[4];
#pragma unroll
        for (int nt = 0; nt < 4; nt++) accS[nt] = zero;
#pragma unroll
        for (int nt = 0; nt < 4; nt++) {
#pragma unroll
            for (int ksp = 0; ksp < 2; ksp++) {
                bf16x8 bk = *(const bf16x8*)&sK[cur][((ksp * 4 + quad) * 64 + nt * 16 + m) * 8];
                accS[nt] = __builtin_amdgcn_mfma_f32_16x16x32_bf16(qhi[ksp], bk, accS[nt], 0, 0, 0);
                accS[nt] = __builtin_amdgcn_mfma_f32_16x16x32_bf16(qlo[ksp], bk, accS[nt], 0, 0, 0);
            }
        }
#pragma unroll
        for (int half = 0; half < 2; half++) {
#pragma unroll
            for (int nt = 2 * half; nt < 2 * half + 2; nt++) {
                int col = nt * 16 + m;
                int sglob = sb + col;
                float ktv = skt[cur][col], vtv = svt[cur][col];
#pragma unroll
                for (int r = 0; r < 4; r++) {
                    float ratio = fmaxf(fmaf(qtv[r], ktv, -accS[nt][r]), 1.0f + 1e-7f);
                    float y = ratio + fsqrt_(fmaf(ratio, ratio, -1.0f));
                    float pv = fexp2(msqK * flog2(y));
                    float p = (sglob <= qg[r]) ? pv : 0.0f;
                    lsumr[r] += p;
                    o0r[r] = fmaf(p, vtv, o0r[r]);
                    sPw[(quad * 4 + r) * 72 + col] = (__bf16)p;
                }
            }
            __asm__ volatile("s_waitcnt lgkmcnt(0)" ::: "memory");
            {
                bf16x8 aP = *(const bf16x8*)&sPw[m * 72 + half * 32 + quad * 8];
#pragma unroll
                for (int nt = 0; nt < 4; nt++) {
                    bf16x8 bV = *(const bf16x8*)&sVt[cur][((half * 4 + quad) * 64 + nt * 16 + m) * 8];
                    accO[nt] = __builtin_amdgcn_mfma_f32_16x16x32_bf16(aP, bV, accO[nt], 0, 0, 0);
                }
            }
        }
    }

    // ---- final: reduce lsum/o0 over the 16 col-lanes, normalize, write ----
#pragma unroll
    for (int r = 0; r < 4; r++) {
#pragma unroll
        for (int off = 1; off < 16; off <<= 1) {
            lsumr[r] += __shfl_xor(lsumr[r], off);
            o0r[r]   += __shfl_xor(o0r[r], off);
        }
    }
#pragma unroll
    for (int r = 0; r < 4; r++) {
        float inv = frcp_(lsumr[r]);
        float o0f = o0r[r] * inv;
        float ov[4]; float part = 0.f;
#pragma unroll
        for (int nt = 0; nt < 4; nt++) { float t = accO[nt][r] * inv; ov[nt] = t; part += t * t; }
        part += __shfl_xor(part, 1);
        part += __shfl_xor(part, 2);
        part += __shfl_xor(part, 4);
        part += __shfl_xor(part, 8);
        float scale = sqKh * frsq_(fmaxf(o0f * o0f - part, 1e-12f));
        size_t orow = (size_t)(b * TT + qg[r]) * 1088 + h * 65;
        if (m == 0) O[orow] = (__bf16)(o0f * scale);
#pragma unroll
        for (int nt = 0; nt < 4; nt++) O[orow + 1 + nt * 16 + m] = (__bf16)(ov[nt] * scale);
    }
}

// ---------------------------------------------------------------- launch
extern "C" void kernel_launch(void* const* d_in, const int* in_sizes, int n_in,
                              void* d_out, int out_size, void* d_ws, size_t ws_size,
                              hipStream_t stream) {
    const float* x    = (const float*)d_in[0];
    const float* bc   = (const float*)d_in[1];
    const float* mc   = (const float*)d_in[2];
    const float* ac   = (const float*)d_in[3];
    const float* w_qkv = (const float*)d_in[4];
    const float* w_ap  = (const float*)d_in[5];
    const float* b_ap  = (const float*)d_in[6];
    const float* w_me  = (const float*)d_in[7];
    const float* b_me  = (const float*)d_in[8];
    const float* w_ms  = (const float*)d_in[9];
    const float* b_ms  = (const float*)d_in[10];
    const float* lnw  = (const float*)d_in[11];
    const float* lnb  = (const float*)d_in[12];
    float* out = (float*)d_out;
    float* ws  = (float*)d_ws;

    // workspace (floats), total ~96.5 MB.
    float* R      = ws;
    float* qkvbuf = R;                             // M*3072 fp32 (dead after flash)
    float* X2     = R;                             // M*1024 fp32 (written step 5)
    __bf16* h_bf  = (__bf16*)(R + 4194304);        // M*4224 bf16 -> ends 12,845,056
    float* p      = R + 12845056;
    __bf16* ln_bf = (__bf16*)p;  p += 2228224;     // M*1088 bf16 (dead after step 8)
    __bf16* o_bf  = (__bf16*)p;  p += 2228224;     // M*1088 bf16 (dead after step 5)
    __bf16* qkvT  = (__bf16*)p;  p += 1671168;     // 3072*1088 bf16 (dead after step 2)
    __bf16* apT   = (__bf16*)p;  p += 557056;      // 1024*1088 bf16 (dead after step 5)
    float*  meT_f = p;           p += 2229856;     // 4099*1088 bf16 (dead after step 8)
    float*  msT_f = p;           p += 2162688;     // 1024*4224 bf16 (after flash)
    float* Qt = p;               p += 2 * HH * TT;
    float* Kt = p;               p += 2 * HH * TT;
    float* Vt = p;
    __bf16* meT = (__bf16*)meT_f;
    __bf16* msT = (__bf16*)msT_f;
    __bf16* Kb  = (__bf16*)meT_f;   // 32*2048*64 bf16 <= meT slot; dead before wt_k(meT)
    __bf16* Vtb = (__bf16*)msT_f;   // same size      <= msT slot; dead before wt_k(msT)
    float* Pbuf = (float*)ln_bf;    // M*1024 fp32 (ln_bf+o_bf slots, written step 9)

    // 0. weight transposes needed before flash (zero-filled past K)
    wt_k<false><<<dim3(34, 96),  256, 0, stream>>>(w_qkv, 1025, 3072, qkvT, 1088);
    wt_k<false><<<dim3(34, 32),  256, 0, stream>>>(w_ap,  1040, 1024, apT,  1088);

    // 1. ln1 = block_norm(project(x)) -> bf16 (stride 1088, zero pad)
    block_norm_bf_k<<<MM, 256, 0, stream>>>(x, 1024, ln_bf, 1088, lnw, lnb, bc);
    // 2. qkv = ln1 @ w_qkv -> fp32 (M,3072)   [256^2 4-deep RING, 192 blocks]
    mgemm256r_k<false, false, false><<<dim3(192), 512, 0, stream>>>(
        ln_bf, 1088, qkvT, 1088, nullptr, qkvbuf, 3072, 3072, 1088, 12);
    // 3a. RoPE (q in place fp32, Kb bf16) + q/k norms + o_bf pad (cols 1040..1087)
    rope_k<<<MM, 256, 0, stream>>>(qkvbuf, ac, Qt, Kt, Kb, o_bf);
    // 3b. V transpose -> Vtb bf16 + v norms
    vtrans_k<<<dim3(32, 32), 256, 0, stream>>>(qkvbuf, ac, Vtb, Vt);
    // 4. MFMA flash attention -> o_t bf16 (M,1088)
    flash_k<<<dim3(2 * HH, 32), 256, 0, stream>>>(qkvbuf, Kb, Vtb, Qt, Kt, Vt, ac, o_bf);
    // 0b. remaining weight transposes (into the slots Kb/Vtb just vacated)
    wt_k<false><<<dim3(34, 129), 256, 0, stream>>>(w_me,  1025, 4099, meT, 1088);
    wt_k<true ><<<dim3(132, 32), 256, 0, stream>>>(w_ms,  4100, 1024, msT, 4224);  // rotated rows
    // 5. lx2[...,1:] = x + o_t @ w_attn_proj + b -> X2 fp32
    mgemm128_k<true, false, true, false><<<dim3(256), 256, 0, stream>>>(
        o_bf, 1088, apT, 1088, b_ap, x, 1024, X2, 1024, 1024, 1088, 8);
    // 6. ln2 = block_norm(lx2) -> bf16
    block_norm_bf_k<<<MM, 256, 0, stream>>>(X2, 1024, ln_bf, 1088, lnw, lnb, bc);
    // 7. h[0..4095] = gelu(ln2 @ w_mlp_expand + b) -> bf16, ALIGNED   [256^2 RING, 256 blocks]
    mgemm256r_k<true, true, true><<<dim3(256), 512, 0, stream>>>(
        ln_bf, 1088, meT, 1088, b_me, (void*)h_bf, 4224, 4096, 1088, 16);
    // 8. h cols 4096..4098 (ragged tail) + x0 col 4099 + pad
    row_x0_tail_k<<<MM, 256, 0, stream>>>(h_bf, ln_bf, meT, b_me, mc);
    // 9. P = lx2[...,1:] + h @ w_mlp_shrink(rot) + b -> aligned fp32 (stride 1024)
    mgemm128_k<true, false, true, false><<<dim3(256), 256, 0, stream>>>(
        h_bf, 4224, msT, 4224, b_ms, X2, 1024, (void*)Pbuf, 1024, 1024, 4224, 8);
    // 10. out[...,1:] = P, out[...,0] = x0 (aligned reads, contiguous row writes)
    out_final_k<<<MM, 256, 0, stream>>>(out, Pbuf, bc);
}